// Round 1
// baseline (6992.627 us; speedup 1.0000x reference)
//
#include <hip/hip_runtime.h>

typedef __bf16 bf16;
typedef __bf16 bf16x4 __attribute__((ext_vector_type(4)));
typedef __bf16 bf16x8 __attribute__((ext_vector_type(8)));
typedef float  f32x4  __attribute__((ext_vector_type(4)));

#define MFMA(a,b,c) __builtin_amdgcn_mfma_f32_16x16x32_bf16((a),(b),(c),0,0,0)

// Problem dims
#define TSTEPS 512
#define NBATCH 128
#define DIN    256
#define DH     1024
#define NRANK  128
#define DOUT   256
#define NG     16      // phase-A workgroups
#define HSL    64      // DH / NG

// Workspace layout (bytes)
#define ZI_OFF    0ull               // bf16 [512*128*1024]  = 134217728 B
#define QSEQ_OFF  134217728ull       // bf16 [512*128*128]   =  16777216 B
#define PBUF_OFF  150994944ull       // bf16 [16*128*128]    =    524288 B
#define WIN_OFF   151519232ull       // bf16 [1024*256]
#define U_OFF     152043520ull       // bf16 [128*1024]
#define V_OFF     152305664ull       // bf16 [1024*128]
#define WOUT_OFF  152567808ull       // bf16 [256*1024]
#define BAR_OFF   153092096ull       // unsigned [16]

// ---------------------------------------------------------------- K0: prep
__global__ __launch_bounds__(256) void k_prep(const float* __restrict__ W_in,
                                              const float* __restrict__ U,
                                              const float* __restrict__ V,
                                              const float* __restrict__ W_out,
                                              char* __restrict__ ws) {
  bf16* winb  = (bf16*)(ws + WIN_OFF);
  bf16* ub    = (bf16*)(ws + U_OFF);
  bf16* vb    = (bf16*)(ws + V_OFF);
  bf16* woutb = (bf16*)(ws + WOUT_OFF);
  bf16* qseq  = (bf16*)(ws + QSEQ_OFF);
  unsigned* bar = (unsigned*)(ws + BAR_OFF);
  size_t id = (size_t)blockIdx.x * 256 + threadIdx.x;
  if      (id < 262144) winb[id]           = (bf16)W_in[id];
  else if (id < 393216) ub[id - 262144]    = (bf16)U[id - 262144];
  else if (id < 524288) vb[id - 393216]    = (bf16)V[id - 393216];
  else if (id < 786432) woutb[id - 524288] = (bf16)W_out[id - 524288];
  else if (id < 802816) qseq[id - 786432]  = (bf16)0.0f;   // q_0 = 0
  else if (id < 802832) bar[id - 802816]   = 0u;           // barrier state
}

// ---------------------------------------------------------------- K1: zi = x @ W_in^T  (bf16 out)
__global__ __launch_bounds__(256) void k_zi(const float* __restrict__ x,
                                            const char* __restrict__ ws,
                                            bf16* __restrict__ zi) {
  const bf16* winb = (const bf16*)(ws + WIN_OFF);
  __shared__ bf16 xl[128 * 264];   // [128][256+8] bf16; reused as [128][136] for C staging
  __shared__ bf16 wl[128 * 264];
  const int tid = threadIdx.x, lane = tid & 63, wv = tid >> 6;
  const int q4 = lane >> 4, l16 = lane & 15;
  const int m0b = blockIdx.x * 128, n0 = blockIdx.y * 128;

  // stage x tile (fp32 -> bf16)
  for (int ch = tid; ch < 8192; ch += 256) {
    int r = ch >> 6, c4 = ch & 63;
    float4 f = *(const float4*)&x[(size_t)(m0b + r) * 256 + c4 * 4];
    bf16x4 b; b[0] = (bf16)f.x; b[1] = (bf16)f.y; b[2] = (bf16)f.z; b[3] = (bf16)f.w;
    *(bf16x4*)&xl[r * 264 + c4 * 4] = b;
  }
  // stage W_in tile (already bf16)
  for (int ch = tid; ch < 4096; ch += 256) {
    int r = ch >> 5, c8 = ch & 31;
    *(uint4*)&wl[r * 264 + c8 * 8] = *(const uint4*)&winb[(size_t)(n0 + r) * 256 + c8 * 8];
  }
  __syncthreads();

  f32x4 z4 = {0.f, 0.f, 0.f, 0.f};
  f32x4 acc[2][8];
#pragma unroll
  for (int i = 0; i < 2; i++)
#pragma unroll
    for (int j = 0; j < 8; j++) acc[i][j] = z4;

  const int m0 = wv * 32;
#pragma unroll
  for (int kc = 0; kc < 8; kc++) {
    bf16x8 a0 = *(bf16x8*)&xl[(m0 + l16) * 264 + kc * 32 + q4 * 8];
    bf16x8 a1 = *(bf16x8*)&xl[(m0 + 16 + l16) * 264 + kc * 32 + q4 * 8];
#pragma unroll
    for (int nt = 0; nt < 8; nt++) {
      bf16x8 b = *(bf16x8*)&wl[(nt * 16 + l16) * 264 + kc * 32 + q4 * 8];
      acc[0][nt] = MFMA(a0, b, acc[0][nt]);
      acc[1][nt] = MFMA(a1, b, acc[1][nt]);
    }
  }
  __syncthreads();
  // C -> LDS (bf16) then vectorized store
#pragma unroll
  for (int mt = 0; mt < 2; mt++)
#pragma unroll
    for (int nt = 0; nt < 8; nt++)
#pragma unroll
      for (int r = 0; r < 4; r++) {
        int m = m0 + mt * 16 + q4 * 4 + r;
        int c = nt * 16 + l16;
        xl[m * 136 + c] = (bf16)acc[mt][nt][r];
      }
  __syncthreads();
  for (int ch = tid; ch < 2048; ch += 256) {
    int r = ch >> 4, c8 = ch & 15;
    *(uint4*)&zi[(size_t)(m0b + r) * 1024 + n0 + c8 * 8] = *(uint4*)&xl[r * 136 + c8 * 8];
  }
}

// ---------------------------------------------------------------- device barrier (agent scope)
__device__ inline void gbar(unsigned* bar) {
  __syncthreads();
  if (threadIdx.x == 0) {
    __threadfence();  // release my block's stores to agent scope
    unsigned g0 = __hip_atomic_load(&bar[1], __ATOMIC_RELAXED, __HIP_MEMORY_SCOPE_AGENT);
    unsigned prev = __hip_atomic_fetch_add(&bar[0], 1u, __ATOMIC_ACQ_REL, __HIP_MEMORY_SCOPE_AGENT);
    if (prev == NG - 1) {
      __hip_atomic_store(&bar[0], 0u, __ATOMIC_RELAXED, __HIP_MEMORY_SCOPE_AGENT);
      __hip_atomic_store(&bar[1], g0 + 1u, __ATOMIC_RELEASE, __HIP_MEMORY_SCOPE_AGENT);
    } else {
      while (__hip_atomic_load(&bar[1], __ATOMIC_RELAXED, __HIP_MEMORY_SCOPE_AGENT) == g0) {}
    }
    __threadfence();  // acquire: invalidate stale L1/L2 before reading peers' data
  }
  __syncthreads();
}

// ---------------------------------------------------------------- K2: sequential low-rank scan
// 16 blocks; block g owns h-columns [g*64, g*64+64). State q_t [128,128] replicated in LDS.
__global__ __launch_bounds__(256) void k_phaseA(char* __restrict__ ws, const float* __restrict__ b_h) {
  const bf16* zi  = (const bf16*)(ws + ZI_OFF);
  bf16* qseq      = (bf16*)(ws + QSEQ_OFF);
  bf16* pbuf      = (bf16*)(ws + PBUF_OFF);
  const bf16* ub  = (const bf16*)(ws + U_OFF);
  const bf16* vb  = (const bf16*)(ws + V_OFF);
  unsigned* bar   = (unsigned*)(ws + BAR_OFF);

  const int g = blockIdx.x;
  const int tid = threadIdx.x, lane = tid & 63, wv = tid >> 6;
  const int q4 = lane >> 4, l16 = lane & 15;

  __shared__ bf16 ql[128 * 136];  // q_t  [128 b][128 r]
  __shared__ bf16 vl[64 * 136];   // V[g*64+nl][r]      (B for stage2)
  __shared__ bf16 ul[128 * 72];   // U[r][g*64+kl]      (B for stage1)
  __shared__ bf16 hl[128 * 72];   // h slice [128 b][64]
  __shared__ bf16 zl[128 * 72];   // zi slice
  __shared__ float bl[64];

  for (int ch = tid; ch < 1024; ch += 256) {   // V slice: 64 rows x 16 chunks
    int r = ch >> 4, c8 = ch & 15;
    *(uint4*)&vl[r * 136 + c8 * 8] = *(const uint4*)&vb[(size_t)(g * 64 + r) * 128 + c8 * 8];
  }
  for (int ch = tid; ch < 1024; ch += 256) {   // U slice: 128 rows x 8 chunks
    int r = ch >> 3, c8 = ch & 7;
    *(uint4*)&ul[r * 72 + c8 * 8] = *(const uint4*)&ub[(size_t)r * 1024 + g * 64 + c8 * 8];
  }
  if (tid < 64) bl[tid] = b_h[g * 64 + tid];
  for (int i = tid; i < 128 * 136; i += 256) ql[i] = (bf16)0.0f;  // q_0 = 0
  __syncthreads();

  const int m0 = wv * 32;
  const f32x4 z4 = {0.f, 0.f, 0.f, 0.f};

  for (int t = 0; t < TSTEPS - 1 + 0; t++) {   // t = 0..510 produce q_1..q_511; plus t covers all needed
    if (t >= 511) break;
    // stage zi[t][:, g*64:+64]
    for (int ch = tid; ch < 1024; ch += 256) {
      int r = ch >> 3, c8 = ch & 7;
      *(uint4*)&zl[r * 72 + c8 * 8] = *(const uint4*)&zi[((size_t)t * 128 + r) * 1024 + g * 64 + c8 * 8];
    }
    __syncthreads();

    // stage2: zh[128][64] = q @ V_g^T
    f32x4 acc2[2][4];
#pragma unroll
    for (int i = 0; i < 2; i++)
#pragma unroll
      for (int j = 0; j < 4; j++) acc2[i][j] = z4;
#pragma unroll
    for (int kc = 0; kc < 4; kc++) {
      bf16x8 a0 = *(bf16x8*)&ql[(m0 + l16) * 136 + kc * 32 + q4 * 8];
      bf16x8 a1 = *(bf16x8*)&ql[(m0 + 16 + l16) * 136 + kc * 32 + q4 * 8];
#pragma unroll
      for (int nt = 0; nt < 4; nt++) {
        bf16x8 b = *(bf16x8*)&vl[(nt * 16 + l16) * 136 + kc * 32 + q4 * 8];
        acc2[0][nt] = MFMA(a0, b, acc2[0][nt]);
        acc2[1][nt] = MFMA(a1, b, acc2[1][nt]);
      }
    }
    // relu(zh + b + zi) -> hl
#pragma unroll
    for (int mt = 0; mt < 2; mt++)
#pragma unroll
      for (int nt = 0; nt < 4; nt++)
#pragma unroll
        for (int r = 0; r < 4; r++) {
          int m = m0 + mt * 16 + q4 * 4 + r;
          int c = nt * 16 + l16;
          float v = acc2[mt][nt][r] + bl[c] + (float)zl[m * 72 + c];
          hl[m * 72 + c] = (bf16)fmaxf(v, 0.0f);
        }
    __syncthreads();

    // stage1: q'_partial[128][128] = h_slice @ U_g^T  (K = 64)
    f32x4 acc1[2][8];
#pragma unroll
    for (int i = 0; i < 2; i++)
#pragma unroll
      for (int j = 0; j < 8; j++) acc1[i][j] = z4;
#pragma unroll
    for (int kc = 0; kc < 2; kc++) {
      bf16x8 a0 = *(bf16x8*)&hl[(m0 + l16) * 72 + kc * 32 + q4 * 8];
      bf16x8 a1 = *(bf16x8*)&hl[(m0 + 16 + l16) * 72 + kc * 32 + q4 * 8];
#pragma unroll
      for (int nt = 0; nt < 8; nt++) {
        bf16x8 b = *(bf16x8*)&ul[(nt * 16 + l16) * 72 + kc * 32 + q4 * 8];
        acc1[0][nt] = MFMA(a0, b, acc1[0][nt]);
        acc1[1][nt] = MFMA(a1, b, acc1[1][nt]);
      }
    }
    __syncthreads();
    // partial -> ql (staging for vectorized store; q_t no longer needed)
#pragma unroll
    for (int mt = 0; mt < 2; mt++)
#pragma unroll
      for (int nt = 0; nt < 8; nt++)
#pragma unroll
        for (int r = 0; r < 4; r++) {
          int m = m0 + mt * 16 + q4 * 4 + r;
          int c = nt * 16 + l16;
          ql[m * 136 + c] = (bf16)acc1[mt][nt][r];
        }
    __syncthreads();
    for (int ch = tid; ch < 2048; ch += 256) {
      int r = ch >> 4, c8 = ch & 15;
      *(uint4*)&pbuf[(size_t)g * 16384 + r * 128 + c8 * 8] = *(uint4*)&ql[r * 136 + c8 * 8];
    }
    gbar(bar);
    // reduce my 8 rows across 16 partials -> q_{t+1}
    {
      int idx = g * 1024 + tid * 4;
      float s0 = 0.f, s1 = 0.f, s2 = 0.f, s3 = 0.f;
#pragma unroll
      for (int p = 0; p < NG; p++) {
        bf16x4 v = *(const bf16x4*)&pbuf[(size_t)p * 16384 + idx];
        s0 += (float)v[0]; s1 += (float)v[1]; s2 += (float)v[2]; s3 += (float)v[3];
      }
      bf16x4 o; o[0] = (bf16)s0; o[1] = (bf16)s1; o[2] = (bf16)s2; o[3] = (bf16)s3;
      *(bf16x4*)&qseq[(size_t)(t + 1) * 16384 + idx] = o;
    }
    gbar(bar);
    // reload full q_{t+1}
    for (int ch = tid; ch < 2048; ch += 256) {
      int r = ch >> 4, c8 = ch & 15;
      *(uint4*)&ql[r * 136 + c8 * 8] = *(const uint4*)&qseq[(size_t)(t + 1) * 16384 + r * 128 + c8 * 8];
    }
    __syncthreads();
  }
}

// ---------------------------------------------------------------- K3: hidden[t] = relu(q_t V^T + b + zi_t)  (fp32 out)
__global__ __launch_bounds__(256) void k_hidden(const char* __restrict__ ws,
                                                const float* __restrict__ b_h,
                                                float* __restrict__ hid) {
  const bf16* qseq = (const bf16*)(ws + QSEQ_OFF);
  const bf16* vb   = (const bf16*)(ws + V_OFF);
  const bf16* zi   = (const bf16*)(ws + ZI_OFF);
  const int t = blockIdx.x, n0 = blockIdx.y * 128;
  const int tid = threadIdx.x, lane = tid & 63, wv = tid >> 6;
  const int q4 = lane >> 4, l16 = lane & 15;

  __shared__ bf16 ql2[128 * 136];
  __shared__ bf16 vl2[128 * 136];
  __shared__ bf16 zl2[128 * 136];
  __shared__ float bl2[128];

  for (int ch = tid; ch < 2048; ch += 256) {
    int r = ch >> 4, c8 = ch & 15;
    *(uint4*)&ql2[r * 136 + c8 * 8] = *(const uint4*)&qseq[(size_t)t * 16384 + r * 128 + c8 * 8];
    *(uint4*)&vl2[r * 136 + c8 * 8] = *(const uint4*)&vb[(size_t)(n0 + r) * 128 + c8 * 8];
    *(uint4*)&zl2[r * 136 + c8 * 8] = *(const uint4*)&zi[((size_t)t * 128 + r) * 1024 + n0 + c8 * 8];
  }
  if (tid < 128) bl2[tid] = b_h[n0 + tid];
  __syncthreads();

  f32x4 z4 = {0.f, 0.f, 0.f, 0.f};
  f32x4 acc[2][8];
#pragma unroll
  for (int i = 0; i < 2; i++)
#pragma unroll
    for (int j = 0; j < 8; j++) acc[i][j] = z4;

  const int m0 = wv * 32;
#pragma unroll
  for (int kc = 0; kc < 4; kc++) {
    bf16x8 a0 = *(bf16x8*)&ql2[(m0 + l16) * 136 + kc * 32 + q4 * 8];
    bf16x8 a1 = *(bf16x8*)&ql2[(m0 + 16 + l16) * 136 + kc * 32 + q4 * 8];
#pragma unroll
    for (int nt = 0; nt < 8; nt++) {
      bf16x8 b = *(bf16x8*)&vl2[(nt * 16 + l16) * 136 + kc * 32 + q4 * 8];
      acc[0][nt] = MFMA(a0, b, acc[0][nt]);
      acc[1][nt] = MFMA(a1, b, acc[1][nt]);
    }
  }
#pragma unroll
  for (int mt = 0; mt < 2; mt++)
#pragma unroll
    for (int nt = 0; nt < 8; nt++)
#pragma unroll
      for (int r = 0; r < 4; r++) {
        int m = m0 + mt * 16 + q4 * 4 + r;
        int c = nt * 16 + l16;
        float v = acc[mt][nt][r] + bl2[c] + (float)zl2[m * 136 + c];
        hid[((size_t)t * 128 + m) * 1024 + n0 + c] = fmaxf(v, 0.0f);
      }
}

// ---------------------------------------------------------------- K4: output = hidden @ W_out^T + b_out
__global__ __launch_bounds__(512) void k_out(const char* __restrict__ ws,
                                             const float* __restrict__ hid,
                                             const float* __restrict__ b_out,
                                             float* __restrict__ out) {
  const bf16* woutb = (const bf16*)(ws + WOUT_OFF);
  const int t = blockIdx.x;
  const int tid = threadIdx.x, lane = tid & 63, wv = tid >> 6;  // 8 waves
  const int q4 = lane >> 4, l16 = lane & 15;

  __shared__ bf16 hl2[128 * 136];
  __shared__ bf16 wl2[256 * 136];
  __shared__ float bol[256];
  if (tid < 256) bol[tid] = b_out[tid];

  f32x4 z4 = {0.f, 0.f, 0.f, 0.f};
  f32x4 acc[16];
#pragma unroll
  for (int j = 0; j < 16; j++) acc[j] = z4;

  const int m0 = wv * 16;
  for (int k0 = 0; k0 < 1024; k0 += 128) {
    __syncthreads();
    for (int ch = tid; ch < 4096; ch += 512) {
      int r = ch >> 5, c4 = ch & 31;
      float4 f = *(const float4*)&hid[((size_t)t * 128 + r) * 1024 + k0 + c4 * 4];
      bf16x4 b; b[0] = (bf16)f.x; b[1] = (bf16)f.y; b[2] = (bf16)f.z; b[3] = (bf16)f.w;
      *(bf16x4*)&hl2[r * 136 + c4 * 4] = b;
    }
    for (int ch = tid; ch < 4096; ch += 512) {
      int r = ch >> 4, c8 = ch & 15;
      *(uint4*)&wl2[r * 136 + c8 * 8] = *(const uint4*)&woutb[(size_t)r * 1024 + k0 + c8 * 8];
    }
    __syncthreads();
#pragma unroll
    for (int kc = 0; kc < 4; kc++) {
      bf16x8 a = *(bf16x8*)&hl2[(m0 + l16) * 136 + kc * 32 + q4 * 8];
#pragma unroll
      for (int nt = 0; nt < 16; nt++) {
        bf16x8 b = *(bf16x8*)&wl2[(nt * 16 + l16) * 136 + kc * 32 + q4 * 8];
        acc[nt] = MFMA(a, b, acc[nt]);
      }
    }
  }
#pragma unroll
  for (int nt = 0; nt < 16; nt++)
#pragma unroll
    for (int r = 0; r < 4; r++) {
      int m = m0 + q4 * 4 + r;
      int c = nt * 16 + l16;
      out[((size_t)t * 128 + m) * 256 + c] = acc[nt][r] + bol[c];
    }
}

// ---------------------------------------------------------------- launch
extern "C" void kernel_launch(void* const* d_in, const int* in_sizes, int n_in,
                              void* d_out, int out_size, void* d_ws, size_t ws_size,
                              hipStream_t stream) {
  (void)in_sizes; (void)n_in; (void)out_size; (void)ws_size;
  const float* x     = (const float*)d_in[0];
  const float* W_in  = (const float*)d_in[1];
  const float* U     = (const float*)d_in[2];
  const float* V     = (const float*)d_in[3];
  const float* b_h   = (const float*)d_in[4];
  const float* W_out = (const float*)d_in[5];
  const float* b_out = (const float*)d_in[6];
  char* ws = (char*)d_ws;
  float* hid = (float*)d_out;
  float* out = hid + (size_t)TSTEPS * NBATCH * DH;
  bf16* zi = (bf16*)(ws + ZI_OFF);

  k_prep<<<dim3(3137), dim3(256), 0, stream>>>(W_in, U, V, W_out, ws);
  k_zi<<<dim3(512, 8), dim3(256), 0, stream>>>(x, ws, zi);
  k_phaseA<<<dim3(NG), dim3(256), 0, stream>>>(ws, b_h);
  k_hidden<<<dim3(512, 8), dim3(256), 0, stream>>>(ws, b_h, hid);
  k_out<<<dim3(512), dim3(512), 0, stream>>>(ws, hid, b_out, out);
}

// Round 2
// 6439.650 us; speedup vs baseline: 1.0859x; 1.0859x over previous
//
#include <hip/hip_runtime.h>

typedef __bf16 bf16;
typedef __bf16 bf16x4 __attribute__((ext_vector_type(4)));
typedef __bf16 bf16x8 __attribute__((ext_vector_type(8)));
typedef float  f32x4  __attribute__((ext_vector_type(4)));
typedef unsigned long long u64;

#define MFMA(a,b,c) __builtin_amdgcn_mfma_f32_16x16x32_bf16((a),(b),(c),0,0,0)

// Problem dims
#define TSTEPS 512
#define NBATCH 128
#define DIN    256
#define DH     1024
#define NRANK  128
#define DOUT   256
#define NG     16      // phase-A workgroups
#define HSL    64      // DH / NG

// Workspace layout (bytes) — unchanged from round 1 (ws_size proven sufficient)
#define ZI_OFF    0ull               // bf16 [512*128*1024]  = 134217728 B
#define QSEQ_OFF  134217728ull       // bf16 [512*128*128]   =  16777216 B
#define PBUF_OFF  150994944ull       // bf16 [16*128*128]    =    524288 B
#define WIN_OFF   151519232ull       // bf16 [1024*256]
#define U_OFF     152043520ull       // bf16 [128*1024]
#define V_OFF     152305664ull       // bf16 [1024*128]
#define WOUT_OFF  152567808ull       // bf16 [256*1024]
#define BAR_OFF   153092096ull       // unsigned [16] all-to-all flags

// Coherent (agent-scope, cache-bypassing) 8-byte access helpers.
// Relaxed atomics compile to global_load/store_dwordx2 with sc0 sc1 —
// they hit the coherence point directly, so NO acquire/release fences
// (and no buffer_inv L2 invalidation) are needed anywhere.
__device__ __forceinline__ void cstore64(u64* p, u64 v) {
  __hip_atomic_store(p, v, __ATOMIC_RELAXED, __HIP_MEMORY_SCOPE_AGENT);
}
__device__ __forceinline__ u64 cload64(const u64* p) {
  return __hip_atomic_load(p, __ATOMIC_RELAXED, __HIP_MEMORY_SCOPE_AGENT);
}
union B4U { u64 u; bf16x4 b; };

// ---------------------------------------------------------------- K0: prep
__global__ __launch_bounds__(256) void k_prep(const float* __restrict__ W_in,
                                              const float* __restrict__ U,
                                              const float* __restrict__ V,
                                              const float* __restrict__ W_out,
                                              char* __restrict__ ws) {
  bf16* winb  = (bf16*)(ws + WIN_OFF);
  bf16* ub    = (bf16*)(ws + U_OFF);
  bf16* vb    = (bf16*)(ws + V_OFF);
  bf16* woutb = (bf16*)(ws + WOUT_OFF);
  bf16* qseq  = (bf16*)(ws + QSEQ_OFF);
  unsigned* bar = (unsigned*)(ws + BAR_OFF);
  size_t id = (size_t)blockIdx.x * 256 + threadIdx.x;
  if      (id < 262144) winb[id]           = (bf16)W_in[id];
  else if (id < 393216) ub[id - 262144]    = (bf16)U[id - 262144];
  else if (id < 524288) vb[id - 393216]    = (bf16)V[id - 393216];
  else if (id < 786432) woutb[id - 524288] = (bf16)W_out[id - 524288];
  else if (id < 802816) qseq[id - 786432]  = (bf16)0.0f;   // q_0 = 0
  else if (id < 802832) bar[id - 802816]   = 0u;           // flags
}

// ---------------------------------------------------------------- K1: zi = x @ W_in^T  (bf16 out)
__global__ __launch_bounds__(256) void k_zi(const float* __restrict__ x,
                                            const char* __restrict__ ws,
                                            bf16* __restrict__ zi) {
  const bf16* winb = (const bf16*)(ws + WIN_OFF);
  __shared__ bf16 xl[128 * 264];
  __shared__ bf16 wl[128 * 264];
  const int tid = threadIdx.x, lane = tid & 63, wv = tid >> 6;
  const int q4 = lane >> 4, l16 = lane & 15;
  const int m0b = blockIdx.x * 128, n0 = blockIdx.y * 128;

  for (int ch = tid; ch < 8192; ch += 256) {
    int r = ch >> 6, c4 = ch & 63;
    float4 f = *(const float4*)&x[(size_t)(m0b + r) * 256 + c4 * 4];
    bf16x4 b; b[0] = (bf16)f.x; b[1] = (bf16)f.y; b[2] = (bf16)f.z; b[3] = (bf16)f.w;
    *(bf16x4*)&xl[r * 264 + c4 * 4] = b;
  }
  for (int ch = tid; ch < 4096; ch += 256) {
    int r = ch >> 5, c8 = ch & 31;
    *(uint4*)&wl[r * 264 + c8 * 8] = *(const uint4*)&winb[(size_t)(n0 + r) * 256 + c8 * 8];
  }
  __syncthreads();

  f32x4 z4 = {0.f, 0.f, 0.f, 0.f};
  f32x4 acc[2][8];
#pragma unroll
  for (int i = 0; i < 2; i++)
#pragma unroll
    for (int j = 0; j < 8; j++) acc[i][j] = z4;

  const int m0 = wv * 32;
#pragma unroll
  for (int kc = 0; kc < 8; kc++) {
    bf16x8 a0 = *(bf16x8*)&xl[(m0 + l16) * 264 + kc * 32 + q4 * 8];
    bf16x8 a1 = *(bf16x8*)&xl[(m0 + 16 + l16) * 264 + kc * 32 + q4 * 8];
#pragma unroll
    for (int nt = 0; nt < 8; nt++) {
      bf16x8 b = *(bf16x8*)&wl[(nt * 16 + l16) * 264 + kc * 32 + q4 * 8];
      acc[0][nt] = MFMA(a0, b, acc[0][nt]);
      acc[1][nt] = MFMA(a1, b, acc[1][nt]);
    }
  }
  __syncthreads();
#pragma unroll
  for (int mt = 0; mt < 2; mt++)
#pragma unroll
    for (int nt = 0; nt < 8; nt++)
#pragma unroll
      for (int r = 0; r < 4; r++) {
        int m = m0 + mt * 16 + q4 * 4 + r;
        int c = nt * 16 + l16;
        xl[m * 136 + c] = (bf16)acc[mt][nt][r];
      }
  __syncthreads();
  for (int ch = tid; ch < 2048; ch += 256) {
    int r = ch >> 4, c8 = ch & 15;
    *(uint4*)&zi[(size_t)(m0b + r) * 1024 + n0 + c8 * 8] = *(uint4*)&xl[r * 136 + c8 * 8];
  }
}

// ---------------------------------------------------------------- K2: sequential low-rank scan
// 16 blocks; block g owns h-columns [g*64, g*64+64). Fence-free flag sync.
__global__ __launch_bounds__(256) void k_phaseA(char* __restrict__ ws, const float* __restrict__ b_h) {
  const bf16* zi  = (const bf16*)(ws + ZI_OFF);
  const bf16* ub  = (const bf16*)(ws + U_OFF);
  const bf16* vb  = (const bf16*)(ws + V_OFF);
  u64* pbufq      = (u64*)(ws + PBUF_OFF);    // [16][4096] u64 (= [16][128][128] bf16)
  u64* qseqq      = (u64*)(ws + QSEQ_OFF);    // [512][4096] u64
  unsigned* flag  = (unsigned*)(ws + BAR_OFF);

  const int g = blockIdx.x;
  const int tid = threadIdx.x, lane = tid & 63, wv = tid >> 6;
  const int q4 = lane >> 4, l16 = lane & 15;

  __shared__ bf16 ql[128 * 136];  // q_t  [128 b][128 r]
  __shared__ bf16 vl[64 * 136];   // V[g*64+nl][r]
  __shared__ bf16 ul[128 * 72];   // U[r][g*64+kl]
  __shared__ bf16 hl[128 * 72];   // h slice
  __shared__ bf16 zl[128 * 72];   // zi slice
  __shared__ float bl[64];

  for (int ch = tid; ch < 1024; ch += 256) {
    int r = ch >> 4, c8 = ch & 15;
    *(uint4*)&vl[r * 136 + c8 * 8] = *(const uint4*)&vb[(size_t)(g * 64 + r) * 128 + c8 * 8];
  }
  for (int ch = tid; ch < 1024; ch += 256) {
    int r = ch >> 3, c8 = ch & 7;
    *(uint4*)&ul[r * 72 + c8 * 8] = *(const uint4*)&ub[(size_t)r * 1024 + g * 64 + c8 * 8];
  }
  if (tid < 64) bl[tid] = b_h[g * 64 + tid];
  for (int i = tid; i < 128 * 136; i += 256) ql[i] = (bf16)0.0f;  // q_0 = 0
  // stage zi[0]
  for (int ch = tid; ch < 1024; ch += 256) {
    int r = ch >> 3, c8 = ch & 7;
    *(uint4*)&zl[r * 72 + c8 * 8] = *(const uint4*)&zi[((size_t)0 * 128 + r) * 1024 + g * 64 + c8 * 8];
  }
  __syncthreads();

  const int m0 = wv * 32;
  const f32x4 z4 = {0.f, 0.f, 0.f, 0.f};

  for (int t = 0; t < TSTEPS - 1; t++) {
    // ---- stage2: zh[128][64] = q_t @ V_g^T ; h = relu(zh + b + zi_t)
    f32x4 acc2[2][4];
#pragma unroll
    for (int i = 0; i < 2; i++)
#pragma unroll
      for (int j = 0; j < 4; j++) acc2[i][j] = z4;
#pragma unroll
    for (int kc = 0; kc < 4; kc++) {
      bf16x8 a0 = *(bf16x8*)&ql[(m0 + l16) * 136 + kc * 32 + q4 * 8];
      bf16x8 a1 = *(bf16x8*)&ql[(m0 + 16 + l16) * 136 + kc * 32 + q4 * 8];
#pragma unroll
      for (int nt = 0; nt < 4; nt++) {
        bf16x8 b = *(bf16x8*)&vl[(nt * 16 + l16) * 136 + kc * 32 + q4 * 8];
        acc2[0][nt] = MFMA(a0, b, acc2[0][nt]);
        acc2[1][nt] = MFMA(a1, b, acc2[1][nt]);
      }
    }
#pragma unroll
    for (int mt = 0; mt < 2; mt++)
#pragma unroll
      for (int nt = 0; nt < 4; nt++)
#pragma unroll
        for (int r = 0; r < 4; r++) {
          int m = m0 + mt * 16 + q4 * 4 + r;
          int c = nt * 16 + l16;
          float v = acc2[mt][nt][r] + bl[c] + (float)zl[m * 72 + c];
          hl[m * 72 + c] = (bf16)fmaxf(v, 0.0f);
        }
    __syncthreads();   // hl ready; zl fully consumed

    // ---- stage1: q'_partial[128][128] = h_slice @ U_g^T  (K = 64)
    f32x4 acc1[2][8];
#pragma unroll
    for (int i = 0; i < 2; i++)
#pragma unroll
      for (int j = 0; j < 8; j++) acc1[i][j] = z4;
#pragma unroll
    for (int kc = 0; kc < 2; kc++) {
      bf16x8 a0 = *(bf16x8*)&hl[(m0 + l16) * 72 + kc * 32 + q4 * 8];
      bf16x8 a1 = *(bf16x8*)&hl[(m0 + 16 + l16) * 72 + kc * 32 + q4 * 8];
#pragma unroll
      for (int nt = 0; nt < 8; nt++) {
        bf16x8 b = *(bf16x8*)&ul[(nt * 16 + l16) * 72 + kc * 32 + q4 * 8];
        acc1[0][nt] = MFMA(a0, b, acc1[0][nt]);
        acc1[1][nt] = MFMA(a1, b, acc1[1][nt]);
      }
    }
    __syncthreads();   // everyone done reading ql (stage2) — safe to overwrite
#pragma unroll
    for (int mt = 0; mt < 2; mt++)
#pragma unroll
      for (int nt = 0; nt < 8; nt++)
#pragma unroll
        for (int r = 0; r < 4; r++) {
          int m = m0 + mt * 16 + q4 * 4 + r;
          int c = nt * 16 + l16;
          ql[m * 136 + c] = (bf16)acc1[mt][nt][r];
        }
    __syncthreads();   // ql staging complete

    // ---- post partial: coherent stores LDS -> pbuf[g]
    for (int ch = tid; ch < 4096; ch += 256) {
      int r = ch >> 5, c4 = ch & 31;
      u64 v = *(u64*)&ql[r * 136 + c4 * 4];
      cstore64(&pbufq[(size_t)g * 4096 + ch], v);
    }
    // prefetch zi[t+1] into registers (normal cached loads) during sync window
    uint4 pf[4];
#pragma unroll
    for (int i = 0; i < 4; i++) {
      int ch = tid + i * 256;
      int r = ch >> 3, c8 = ch & 7;
      pf[i] = *(const uint4*)&zi[((size_t)(t + 1) * 128 + r) * 1024 + g * 64 + c8 * 8];
    }
    __syncthreads();   // drains vmcnt for ALL waves -> partials visible at coherence point
    if (tid == 0)
      __hip_atomic_store(&flag[g], (unsigned)(2 * t + 1), __ATOMIC_RELEASE, __HIP_MEMORY_SCOPE_AGENT);
    if (tid < NG) {
      while (__hip_atomic_load(&flag[tid], __ATOMIC_RELAXED, __HIP_MEMORY_SCOPE_AGENT) < (unsigned)(2 * t + 1)) {}
    }
    __syncthreads();

    // ---- reduce my slice [g*1024, +1024) across 16 partials -> qseq[t+1] (coherent)
    {
      float s0 = 0.f, s1 = 0.f, s2 = 0.f, s3 = 0.f;
#pragma unroll
      for (int p = 0; p < NG; p++) {
        B4U v; v.u = cload64(&pbufq[(size_t)p * 4096 + g * 256 + tid]);
        s0 += (float)v.b[0]; s1 += (float)v.b[1]; s2 += (float)v.b[2]; s3 += (float)v.b[3];
      }
      B4U o; o.b[0] = (bf16)s0; o.b[1] = (bf16)s1; o.b[2] = (bf16)s2; o.b[3] = (bf16)s3;
      cstore64(&qseqq[(size_t)(t + 1) * 4096 + g * 256 + tid], o.u);
    }
    __syncthreads();   // q-slice stores drained
    if (tid == 0)
      __hip_atomic_store(&flag[g], (unsigned)(2 * t + 2), __ATOMIC_RELEASE, __HIP_MEMORY_SCOPE_AGENT);
    if (tid < NG) {
      while (__hip_atomic_load(&flag[tid], __ATOMIC_RELAXED, __HIP_MEMORY_SCOPE_AGENT) < (unsigned)(2 * t + 2)) {}
    }
    __syncthreads();

    // ---- gather full q_{t+1} (coherent) -> ql ; install prefetched zi[t+1] -> zl
    for (int ch = tid; ch < 4096; ch += 256) {
      u64 v = cload64(&qseqq[(size_t)(t + 1) * 4096 + ch]);
      *(u64*)&ql[(ch >> 5) * 136 + (ch & 31) * 4] = v;
    }
#pragma unroll
    for (int i = 0; i < 4; i++) {
      int ch = tid + i * 256;
      *(uint4*)&zl[(ch >> 3) * 72 + (ch & 7) * 8] = pf[i];
    }
    __syncthreads();   // ql/zl ready for next iteration
  }
}

// ---------------------------------------------------------------- K3: hidden[t] = relu(q_t V^T + b + zi_t)  (fp32 out)
__global__ __launch_bounds__(256) void k_hidden(const char* __restrict__ ws,
                                                const float* __restrict__ b_h,
                                                float* __restrict__ hid) {
  const bf16* qseq = (const bf16*)(ws + QSEQ_OFF);
  const bf16* vb   = (const bf16*)(ws + V_OFF);
  const bf16* zi   = (const bf16*)(ws + ZI_OFF);
  const int t = blockIdx.x, n0 = blockIdx.y * 128;
  const int tid = threadIdx.x, lane = tid & 63, wv = tid >> 6;
  const int q4 = lane >> 4, l16 = lane & 15;

  __shared__ bf16 ql2[128 * 136];
  __shared__ bf16 vl2[128 * 136];
  __shared__ bf16 zl2[128 * 136];
  __shared__ float bl2[128];

  for (int ch = tid; ch < 2048; ch += 256) {
    int r = ch >> 4, c8 = ch & 15;
    *(uint4*)&ql2[r * 136 + c8 * 8] = *(const uint4*)&qseq[(size_t)t * 16384 + r * 128 + c8 * 8];
    *(uint4*)&vl2[r * 136 + c8 * 8] = *(const uint4*)&vb[(size_t)(n0 + r) * 128 + c8 * 8];
    *(uint4*)&zl2[r * 136 + c8 * 8] = *(const uint4*)&zi[((size_t)t * 128 + r) * 1024 + n0 + c8 * 8];
  }
  if (tid < 128) bl2[tid] = b_h[n0 + tid];
  __syncthreads();

  f32x4 z4 = {0.f, 0.f, 0.f, 0.f};
  f32x4 acc[2][8];
#pragma unroll
  for (int i = 0; i < 2; i++)
#pragma unroll
    for (int j = 0; j < 8; j++) acc[i][j] = z4;

  const int m0 = wv * 32;
#pragma unroll
  for (int kc = 0; kc < 4; kc++) {
    bf16x8 a0 = *(bf16x8*)&ql2[(m0 + l16) * 136 + kc * 32 + q4 * 8];
    bf16x8 a1 = *(bf16x8*)&ql2[(m0 + 16 + l16) * 136 + kc * 32 + q4 * 8];
#pragma unroll
    for (int nt = 0; nt < 8; nt++) {
      bf16x8 b = *(bf16x8*)&vl2[(nt * 16 + l16) * 136 + kc * 32 + q4 * 8];
      acc[0][nt] = MFMA(a0, b, acc[0][nt]);
      acc[1][nt] = MFMA(a1, b, acc[1][nt]);
    }
  }
#pragma unroll
  for (int mt = 0; mt < 2; mt++)
#pragma unroll
    for (int nt = 0; nt < 8; nt++)
#pragma unroll
      for (int r = 0; r < 4; r++) {
        int m = m0 + mt * 16 + q4 * 4 + r;
        int c = nt * 16 + l16;
        float v = acc[mt][nt][r] + bl2[c] + (float)zl2[m * 136 + c];
        hid[((size_t)t * 128 + m) * 1024 + n0 + c] = fmaxf(v, 0.0f);
      }
}

// ---------------------------------------------------------------- K4: output = hidden @ W_out^T + b_out
__global__ __launch_bounds__(512) void k_out(const char* __restrict__ ws,
                                             const float* __restrict__ hid,
                                             const float* __restrict__ b_out,
                                             float* __restrict__ out) {
  const bf16* woutb = (const bf16*)(ws + WOUT_OFF);
  const int t = blockIdx.x;
  const int tid = threadIdx.x, lane = tid & 63, wv = tid >> 6;  // 8 waves
  const int q4 = lane >> 4, l16 = lane & 15;

  __shared__ bf16 hl2[128 * 136];
  __shared__ bf16 wl2[256 * 136];
  __shared__ float bol[256];
  if (tid < 256) bol[tid] = b_out[tid];

  f32x4 z4 = {0.f, 0.f, 0.f, 0.f};
  f32x4 acc[16];
#pragma unroll
  for (int j = 0; j < 16; j++) acc[j] = z4;

  const int m0 = wv * 16;
  for (int k0 = 0; k0 < 1024; k0 += 128) {
    __syncthreads();
    for (int ch = tid; ch < 4096; ch += 512) {
      int r = ch >> 5, c4 = ch & 31;
      float4 f = *(const float4*)&hid[((size_t)t * 128 + r) * 1024 + k0 + c4 * 4];
      bf16x4 b; b[0] = (bf16)f.x; b[1] = (bf16)f.y; b[2] = (bf16)f.z; b[3] = (bf16)f.w;
      *(bf16x4*)&hl2[r * 136 + c4 * 4] = b;
    }
    for (int ch = tid; ch < 4096; ch += 512) {
      int r = ch >> 4, c8 = ch & 15;
      *(uint4*)&wl2[r * 136 + c8 * 8] = *(const uint4*)&woutb[(size_t)r * 1024 + k0 + c8 * 8];
    }
    __syncthreads();
#pragma unroll
    for (int kc = 0; kc < 4; kc++) {
      bf16x8 a = *(bf16x8*)&hl2[(m0 + l16) * 136 + kc * 32 + q4 * 8];
#pragma unroll
      for (int nt = 0; nt < 16; nt++) {
        bf16x8 b = *(bf16x8*)&wl2[(nt * 16 + l16) * 136 + kc * 32 + q4 * 8];
        acc[nt] = MFMA(a, b, acc[nt]);
      }
    }
  }
#pragma unroll
  for (int nt = 0; nt < 16; nt++)
#pragma unroll
    for (int r = 0; r < 4; r++) {
      int m = m0 + q4 * 4 + r;
      int c = nt * 16 + l16;
      out[((size_t)t * 128 + m) * 256 + c] = acc[nt][r] + bol[c];
    }
}

// ---------------------------------------------------------------- launch
extern "C" void kernel_launch(void* const* d_in, const int* in_sizes, int n_in,
                              void* d_out, int out_size, void* d_ws, size_t ws_size,
                              hipStream_t stream) {
  (void)in_sizes; (void)n_in; (void)out_size; (void)ws_size;
  const float* x     = (const float*)d_in[0];
  const float* W_in  = (const float*)d_in[1];
  const float* U     = (const float*)d_in[2];
  const float* V     = (const float*)d_in[3];
  const float* b_h   = (const float*)d_in[4];
  const float* W_out = (const float*)d_in[5];
  const float* b_out = (const float*)d_in[6];
  char* ws = (char*)d_ws;
  float* hid = (float*)d_out;
  float* out = hid + (size_t)TSTEPS * NBATCH * DH;
  bf16* zi = (bf16*)(ws + ZI_OFF);

  k_prep<<<dim3(3137), dim3(256), 0, stream>>>(W_in, U, V, W_out, ws);
  k_zi<<<dim3(512, 8), dim3(256), 0, stream>>>(x, ws, zi);
  k_phaseA<<<dim3(NG), dim3(256), 0, stream>>>(ws, b_h);
  k_hidden<<<dim3(512, 8), dim3(256), 0, stream>>>(ws, b_h, hid);
  k_out<<<dim3(512), dim3(512), 0, stream>>>(ws, hid, b_out, out);
}